// Round 8
// baseline (114.038 us; speedup 1.0000x reference)
//
#include <hip/hip_runtime.h>

// out[b,co,h,w] = sum_ci dq( conv3x3(x[b,ci], W[ci,co]) + b[ci,co] )
// Bit-exactness contract (verified R3 absmax==0, R4/R6/R7 absmax=1.4e-6):
//   conv = sequential fmaf over k=(kh*3+kw) ascending, seeded from 0;
//   bias added after as plain f32 add; t = y * (float)(15/9); rintf (half-even);
//   dequant via fmaf(q, 0.6f, .) — post-round, ulp-safe.
// R8: ci split 2-way across grid (rounding stays bit-exact; the post-dequant
// sum over ci is reorder-tolerant: terms are multiples of 0.6, reorder error
// ~1e-5 << 0.43 threshold). Halves combine via HW f32 atomicAdd after a
// hipMemsetAsync zero of d_out. Grid 3136 = 12.25 blocks/CU with
// launch_bounds(256,8): 32 resident waves/CU + queued turnover -> stalls
// hidden by TLP (R6/R7 were stall-bound at 24 waves/CU, no turnover).

constexpr int B_    = 8;
constexpr int CIN   = 16;
constexpr int CIH   = 8;             // ci per grid-half
constexpr int COUT  = 32;
constexpr int H_    = 112;
constexpr int W_    = 112;
constexpr int TILE  = 8;             // 112 = 14*8
constexpr int HALO  = TILE + 2;      // 10
constexpr int LDSW  = 12;            // stride 12: exact 2-way banks (free)
constexpr int COG   = 8;             // co per wave

__global__ __launch_bounds__(256, 8)   // 8 blocks/CU: 8*3.84KB=31KB LDS, 32 waves
void conv_quant_sum_kernel(const float* __restrict__ x,
                           const float* __restrict__ w,
                           const float* __restrict__ bias,
                           float* __restrict__ out)
{
#pragma clang fp contract(off)
    const float QS = (float)(15.0 / 9.0);   // 1.66666663f
    const float DQ = 0.6f;                  // post-round dequant multiplier

    __shared__ float xs[CIH][HALO][LDSW];   // 8*10*12*4 = 3.84 KB

    const int t   = threadIdx.x;
    const int tx  = t & 7;                  // col in 8x8 tile
    const int ty  = (t >> 3) & 7;           // row in 8x8 tile
    // wave id via readfirstlane -> provably wave-uniform -> weight/bias
    // accesses stay scalar s_loads (R5 lesson).
    const int wid = __builtin_amdgcn_readfirstlane(t >> 6);
    const int cog = wid * COG;

    const int tile_x = blockIdx.x * TILE;
    const int tile_y = blockIdx.y * TILE;
    const int b      = blockIdx.z >> 1;
    const int ci0    = (blockIdx.z & 1) * CIH;   // ci half

    // ---- stage x halo tile (10x10 per ci, zero-padded at borders) ----
    const float* xb = x + ((size_t)b * CIN + ci0) * H_ * W_;
    for (int idx = t; idx < CIH * HALO * HALO; idx += 256) {
        int ci  = idx / (HALO * HALO);
        int rem = idx - ci * (HALO * HALO);
        int r   = rem / HALO;
        int c   = rem - r * HALO;
        int gh  = tile_y + r - 1;
        int gw  = tile_x + c - 1;
        float v = 0.0f;
        if ((unsigned)gh < (unsigned)H_ && (unsigned)gw < (unsigned)W_)
            v = xb[ci * H_ * W_ + gh * W_ + gw];
        xs[ci][r][c] = v;
    }
    __syncthreads();

    float acc[COG];
#pragma unroll
    for (int co = 0; co < COG; ++co) acc[co] = 0.0f;

    for (int ci = 0; ci < CIH; ++ci) {
        float xv[9];
#pragma unroll
        for (int r = 0; r < 3; ++r)
#pragma unroll
            for (int c = 0; c < 3; ++c)
                xv[r * 3 + c] = xs[ci][ty + r][tx + c];

        const float* wc = w + (((ci0 + ci) * COUT) + cog) * 9;   // wave-uniform
        const float* bc = bias + (ci0 + ci) * COUT + cog;
#pragma unroll
        for (int co = 0; co < COG; ++co) {
            float s = 0.0f;                       // conv seeded from 0
#pragma unroll
            for (int k = 0; k < 9; ++k)
                s = fmaf(xv[k], wc[co * 9 + k], s);
            float y = s + bc[co];                 // bias: separate f32 add
            float q = rintf(y * QS);              // v_rndne_f32, half-even
            acc[co] = fmaf(q, DQ, acc[co]);       // dequant+sum (post-round)
        }
    }

    // ---- combine the two ci-halves: HW f32 atomicAdd (device scope) ----
    float* ob = out + ((size_t)b * COUT + cog) * H_ * W_;
    const int oh = tile_y + ty;
    const int ow = tile_x + tx;
#pragma unroll
    for (int co = 0; co < COG; ++co)
        atomicAdd(ob + co * H_ * W_ + oh * W_ + ow, acc[co]);
}

extern "C" void kernel_launch(void* const* d_in, const int* in_sizes, int n_in,
                              void* d_out, int out_size, void* d_ws, size_t ws_size,
                              hipStream_t stream)
{
    const float* x    = (const float*)d_in[0];
    const float* w    = (const float*)d_in[1];
    const float* bias = (const float*)d_in[2];
    float* out        = (float*)d_out;

    // zero the accumulation target (graph-capture-legal async memset)
    hipMemsetAsync(out, 0, (size_t)out_size * sizeof(float), stream);

    dim3 grid(W_ / TILE, H_ / TILE, B_ * 2);   // (14, 14, 16) = 3136 blocks
    dim3 block(256);
    conv_quant_sum_kernel<<<grid, block, 0, stream>>>(x, w, bias, out);
}

// Round 9
// 89.514 us; speedup vs baseline: 1.2740x; 1.2740x over previous
//
#include <hip/hip_runtime.h>

// out[b,co,h,w] = sum_ci dq( conv3x3(x[b,ci], W[ci,co]) + b[ci,co] )
// Bit-exactness contract (verified R3 absmax==0, R4/R6/R7 absmax=1.4e-6):
//   conv = sequential fmaf over k=(kh*3+kw) ascending, seeded from 0;
//   bias added after as plain f32 add; t = y * (float)(15/9); rintf (half-even);
//   dequant+sum: fmaf(q, 0.6f, acc), ci ascending. Direct stores (no atomics —
//   R8 showed atomic RMW + memset + staging-dup eats the occupancy gain).
// R9: co split 2-way across grid -> grid 3136 = 12.25 blocks/CU (8 resident
// via launch_bounds(256,8) + queued turnover). Each wave: COG=4 -> halved
// serial chain per wave and halved per-ci SMEM batch (40 dwords) for faster
// lgkm drains. LDS 7.7KB/block; x staged 2x (FETCH ~24MB, trivial).

constexpr int B_    = 8;
constexpr int CIN   = 16;
constexpr int COUT  = 32;
constexpr int H_    = 112;
constexpr int W_    = 112;
constexpr int TILE  = 8;             // 112 = 14*8
constexpr int HALO  = TILE + 2;      // 10
constexpr int LDSW  = 12;            // stride 12: exact 2-way banks (free, m136)
constexpr int COG   = 4;             // co per wave (4 waves x 4 co x 2 grid-halves)

__global__ __launch_bounds__(256, 8)   // 8 blocks/CU resident, 32 waves
void conv_quant_sum_kernel(const float* __restrict__ x,
                           const float* __restrict__ w,
                           const float* __restrict__ bias,
                           float* __restrict__ out)
{
#pragma clang fp contract(off)
    const float QS = (float)(15.0 / 9.0);   // 1.66666663f
    const float DQ = 0.6f;                  // post-round dequant multiplier

    __shared__ float xs[CIN][HALO][LDSW];   // 16*10*12*4 = 7.68 KB

    const int t   = threadIdx.x;
    const int tx  = t & 7;                  // col in 8x8 tile
    const int ty  = (t >> 3) & 7;           // row in 8x8 tile
    // wave id via readfirstlane -> provably wave-uniform -> weight/bias
    // accesses stay scalar s_loads (R5 lesson).
    const int wid = __builtin_amdgcn_readfirstlane(t >> 6);

    const int tile_x = blockIdx.x * TILE;
    const int tile_y = blockIdx.y * TILE;
    const int b      = blockIdx.z >> 1;
    const int cog    = (blockIdx.z & 1) * 16 + wid * COG;   // 0..28 step 4

    // ---- stage x halo tile (10x10 per ci, zero-padded at borders) ----
    const float* xb = x + (size_t)b * CIN * H_ * W_;
    for (int idx = t; idx < CIN * HALO * HALO; idx += 256) {
        int ci  = idx / (HALO * HALO);
        int rem = idx - ci * (HALO * HALO);
        int r   = rem / HALO;
        int c   = rem - r * HALO;
        int gh  = tile_y + r - 1;
        int gw  = tile_x + c - 1;
        float v = 0.0f;
        if ((unsigned)gh < (unsigned)H_ && (unsigned)gw < (unsigned)W_)
            v = xb[ci * H_ * W_ + gh * W_ + gw];
        xs[ci][r][c] = v;
    }
    __syncthreads();

    float acc[COG];
#pragma unroll
    for (int co = 0; co < COG; ++co) acc[co] = 0.0f;

    for (int ci = 0; ci < CIN; ++ci) {
        float xv[9];
#pragma unroll
        for (int r = 0; r < 3; ++r)
#pragma unroll
            for (int c = 0; c < 3; ++c)
                xv[r * 3 + c] = xs[ci][ty + r][tx + c];

        const float* wc = w + (ci * COUT + cog) * 9;   // wave-uniform scalar
        const float* bc = bias + ci * COUT + cog;
#pragma unroll
        for (int co = 0; co < COG; ++co) {
            float s = 0.0f;                       // conv seeded from 0
#pragma unroll
            for (int k = 0; k < 9; ++k)
                s = fmaf(xv[k], wc[co * 9 + k], s);
            float y = s + bc[co];                 // bias: separate f32 add
            float q = rintf(y * QS);              // v_rndne_f32, half-even
            acc[co] = fmaf(q, DQ, acc[co]);       // dequant+sum (post-round)
        }
    }

    float* ob = out + ((size_t)b * COUT + cog) * H_ * W_;
    const int oh = tile_y + ty;
    const int ow = tile_x + tx;
#pragma unroll
    for (int co = 0; co < COG; ++co)
        ob[co * H_ * W_ + oh * W_ + ow] = acc[co];
}

extern "C" void kernel_launch(void* const* d_in, const int* in_sizes, int n_in,
                              void* d_out, int out_size, void* d_ws, size_t ws_size,
                              hipStream_t stream)
{
    const float* x    = (const float*)d_in[0];
    const float* w    = (const float*)d_in[1];
    const float* bias = (const float*)d_in[2];
    float* out        = (float*)d_out;

    dim3 grid(W_ / TILE, H_ / TILE, B_ * 2);   // (14, 14, 16) = 3136 blocks
    dim3 block(256);
    conv_quant_sum_kernel<<<grid, block, 0, stream>>>(x, w, bias, out);
}

// Round 10
// 83.310 us; speedup vs baseline: 1.3688x; 1.0745x over previous
//
#include <hip/hip_runtime.h>

// out[b,co,h,w] = sum_ci dq( conv3x3(x[b,ci], W[ci,co]) + b[ci,co] )
// Bit-exactness contract (verified R3 absmax==0, R4/R6/R7/R9 absmax=1.4e-6):
//   per-pixel conv = sequential fma over k=(kh*3+kw) ascending, seeded from 0;
//   bias after as plain f32 add; t = y * (float)(15/9); rintf (half-even);
//   dequant+sum: fma(q, 0.6f, acc), ci ascending. v_pk_fma_f32 is IEEE per
//   32-bit half -> identical bits per pixel.
// R10: cut the WORK (R4..R9 showed VALU busy-time ~19.7us is the invariant
// limiter; occupancy levers were all neutral). 2 px/thread via packed f32:
// VALU 26->14 instrs per 2 px; LDS 9xb32 -> 3xb64 per px-pair per row-set.
// Tile 16w x 8h = 128 px = one wave at 2px/lane; 4 waves take co-groups
// 0/8/16/24 (readfirstlane -> scalar weight loads; R5 lesson). One staging
// serves all 32 co. launch_bounds(256,4): 128 VGPRs so 8 co-chains interleave
// (R8 lesson: starved allocator serializes everything).

typedef float v2f __attribute__((ext_vector_type(2)));

constexpr int B_    = 8;
constexpr int CIN   = 16;
constexpr int COUT  = 32;
constexpr int H_    = 112;
constexpr int W_    = 112;
constexpr int TW    = 16;            // tile width  (112 = 7*16)
constexpr int TH    = 8;             // tile height (112 = 14*8)
constexpr int HW_   = TW + 2;        // halo width 18
constexpr int HH_   = TH + 2;        // halo height 10
constexpr int LDSW  = 20;            // even row stride (b64 alignment) + pad
constexpr int COG   = 8;             // co per wave

__global__ __launch_bounds__(256, 4)
void conv_quant_sum_kernel(const float* __restrict__ x,
                           const float* __restrict__ w,
                           const float* __restrict__ bias,
                           float* __restrict__ out)
{
#pragma clang fp contract(off)
    const float QS = (float)(15.0 / 9.0);   // 1.66666663f
    const float DQ = 0.6f;                  // post-round dequant multiplier

    __shared__ float xs[CIN][HH_][LDSW];    // 16*10*20*4 = 12.8 KB

    const int t    = threadIdx.x;
    const int lane = t & 63;
    const int tx   = lane & 7;              // pair col: pixels 2tx, 2tx+1
    const int ty   = lane >> 3;             // row 0..7
    const int wid  = __builtin_amdgcn_readfirstlane(t >> 6);
    const int cog  = wid * COG;

    const int tile_x = blockIdx.x * TW;
    const int tile_y = blockIdx.y * TH;
    const int b      = blockIdx.z;

    // ---- stage x halo tile (18x10 per ci, zero-padded at borders) ----
    const float* xb = x + (size_t)b * CIN * H_ * W_;
    for (int idx = t; idx < CIN * HH_ * HW_; idx += 256) {
        int ci  = idx / (HH_ * HW_);
        int rem = idx - ci * (HH_ * HW_);
        int r   = rem / HW_;
        int c   = rem - r * HW_;
        int gh  = tile_y + r - 1;
        int gw  = tile_x + c - 1;
        float v = 0.0f;
        if ((unsigned)gh < (unsigned)H_ && (unsigned)gw < (unsigned)W_)
            v = xb[ci * H_ * W_ + gh * W_ + gw];
        xs[ci][r][c] = v;
    }
    __syncthreads();

    v2f acc[COG];
#pragma unroll
    for (int co = 0; co < COG; ++co) acc[co] = v2f{0.0f, 0.0f};

    for (int ci = 0; ci < CIN; ++ci) {
        // two 3x3 windows from halo cols 2tx..2tx+3, rows ty..ty+2
        v2f xw[3][3];
#pragma unroll
        for (int r = 0; r < 3; ++r) {
            const float* row = &xs[ci][ty + r][2 * tx];
            v2f p0 = *reinterpret_cast<const v2f*>(row);      // b64, 8B-aligned
            v2f p1 = *reinterpret_cast<const v2f*>(row + 2);  // b64
            xw[r][0] = p0;
            xw[r][1] = v2f{p0.y, p1.x};
            xw[r][2] = p1;
        }

        const float* wc = w + (ci * COUT + cog) * 9;   // wave-uniform scalar
        const float* bc = bias + ci * COUT + cog;
#pragma unroll
        for (int co = 0; co < COG; ++co) {
            v2f s = v2f{0.0f, 0.0f};                   // conv seeded from 0
#pragma unroll
            for (int k = 0; k < 9; ++k) {
                float wv = wc[co * 9 + k];
                s = __builtin_elementwise_fma(xw[k / 3][k % 3], v2f{wv, wv}, s);
            }
            float bv = bc[co];
            v2f y  = s + v2f{bv, bv};                  // bias: pk_add
            v2f tq = y * v2f{QS, QS};                  // pk_mul
            v2f q;
            q.x = rintf(tq.x);                         // v_rndne_f32 half-even
            q.y = rintf(tq.y);
            acc[co] = __builtin_elementwise_fma(q, v2f{DQ, DQ}, acc[co]);
        }
    }

    // ---- store: 2 adjacent pixels -> 8B-aligned dwordx2 ----
    float* ob = out + ((size_t)b * COUT + cog) * H_ * W_;
    const int oh = tile_y + ty;
    const int ow = tile_x + 2 * tx;
#pragma unroll
    for (int co = 0; co < COG; ++co)
        *reinterpret_cast<v2f*>(ob + co * H_ * W_ + oh * W_ + ow) = acc[co];
}

extern "C" void kernel_launch(void* const* d_in, const int* in_sizes, int n_in,
                              void* d_out, int out_size, void* d_ws, size_t ws_size,
                              hipStream_t stream)
{
    const float* x    = (const float*)d_in[0];
    const float* w    = (const float*)d_in[1];
    const float* bias = (const float*)d_in[2];
    float* out        = (float*)d_out;

    dim3 grid(W_ / TW, H_ / TH, B_);   // (7, 14, 8) = 784 blocks
    dim3 block(256);
    conv_quant_sum_kernel<<<grid, block, 0, stream>>>(x, w, bias, out);
}